// Round 4
// baseline (109.673 us; speedup 1.0000x reference)
//
#include <hip/hip_runtime.h>
#include <math.h>

#define HW 9216      // 96*96
#define C2 64
#define NSTRIP 288   // HW/32 row-tiles (worst case)
#define NCH 16       // j-chunk count (argmax grid.y)
#define EPSN 1e-8f

typedef _Float16 f16x8  __attribute__((ext_vector_type(8)));
typedef float    f32x16 __attribute__((ext_vector_type(16)));

// ---------------- kernel 1: fused norm + compact + amax-zero ---------------
// Blocks 0..575: row norms (8 lanes/row, shuffle-reduce) + amax zeroing.
// Block 576: compaction (256 threads x 36 positions, shuffle scan).
// ilist/jlist ASCENDING in original position (first-max tie-break compares
// compact j; ascending compact == ascending original). slotmap[p] =
// slot | (flag<<31) lets pack run in position order.
__global__ void prep_kernel(const float* __restrict__ x, const int* __restrict__ mask,
                            int* __restrict__ ilist, int* __restrict__ jlist,
                            int* __restrict__ slotmap, int* __restrict__ counts,
                            float* __restrict__ invAll, unsigned long long* __restrict__ amax) {
    if (blockIdx.x < 576) {
        int t = blockIdx.x * 256 + threadIdx.x;      // 0 .. 2*HW*8-1
        int cc = t & 7;
        int pb = t >> 3;                             // b*HW + p
        int b = pb / HW, p = pb - b * HW;
        const float* xl = x + (size_t)(b * 128 + 64) * HW + p;
        float ss = 0.f;
#pragma unroll
        for (int e = 0; e < 8; e++) { float w = xl[(size_t)(cc * 8 + e) * HW]; ss = fmaf(w, w, ss); }
        ss += __shfl_xor(ss, 1, 64);
        ss += __shfl_xor(ss, 2, 64);
        ss += __shfl_xor(ss, 4, 64);
        if (cc == 0) {
            invAll[pb] = 1.0f / fmaxf(sqrtf(ss), EPSN);
            amax[pb] = 0ull;                         // ws poisoned pre-launch
        }
    } else {
        int t = threadIdx.x;                         // 0..255, each owns 36 positions
        int base = t * 36;
        unsigned long long fl = 0ull; int cnt = 0;
#pragma unroll
        for (int k = 0; k < 36; k++) {
            int f = (mask[base + k] >= 1) ? 1 : 0;
            fl |= (unsigned long long)f << k;
            cnt += f;
        }
        int lane = t & 63, wave = t >> 6;
        int v = cnt;
#pragma unroll
        for (int off = 1; off < 64; off <<= 1) {
            int u = __shfl_up(v, off, 64);
            if (lane >= off) v += u;
        }
        __shared__ int wsum[4];
        if (lane == 63) wsum[wave] = v;
        __syncthreads();
        int woff = 0;
#pragma unroll
        for (int w = 0; w < 4; w++) if (w < wave) woff += wsum[w];
        int incl = v + woff;
        int excl = incl - cnt;
        int posF = excl, posU = base - excl;
#pragma unroll
        for (int k = 0; k < 36; k++) {
            int p = base + k;
            if ((fl >> k) & 1ull) { slotmap[p] = posF | 0x80000000; ilist[posF++] = p; }
            else                  { slotmap[p] = posU;              jlist[posU++] = p; }
        }
        if (t == 255) { counts[0] = incl; counts[1] = HW - incl; }
    }
}

// ---------------- kernel 2: fragment-packed fp16x2 operand prep -----------
// POSITION-ORDER (fully coalesced x reads; each row read exactly once since
// ni+nj = HW). a = ah + al/2048 with ah=fp16(a), al=fp16((a-ah)*2048)
// (residual exact by Sterbenz; x2048 keeps al in fp16 normal range).
// PACKED LAYOUT (must match argmax loads exactly):
//   P[b][tile][ks][lane][e], lane = g*32 + (slot&31), k = ks*16 + g*8 + e.
// Flagged rows -> aH/aL (raw); unflagged -> bH/bL (scaled by f32 inv).
// NO zero-fill: tail-tile slots beyond the counts keep poison; argmax guards
// every use (j<nj scan guard, il<ni commit guard; 0xAA f16 is finite).
__global__ void pack_kernel(const float* __restrict__ x, const int* __restrict__ slotmap,
                            const float* __restrict__ invAll,
                            _Float16* __restrict__ aH, _Float16* __restrict__ aL,
                            _Float16* __restrict__ bH, _Float16* __restrict__ bL) {
    int p = blockIdx.x * 256 + threadIdx.x;      // 0..HW-1 (position)
    int cc = blockIdx.y;                         // 0..7  (ks = cc>>1, g = cc&1)
    int b = blockIdx.z;                          // 0..1
    int sm = slotmap[p];
    int flagged = (sm >> 31) & 1;                // 1 -> a side, 0 -> b side
    int slot = sm & 0x7fffffff;
    const float* xl = x + (size_t)(b * 128 + 64) * HW + p;
    float scale = flagged ? 1.0f : invAll[b * HW + p];
    f16x8 hh, ll;
#pragma unroll
    for (int e = 0; e < 8; e++) {
        float w = xl[(size_t)(cc * 8 + e) * HW] * scale;
        _Float16 h = (_Float16)w;
        hh[e] = h;
        ll[e] = (_Float16)((w - (float)h) * 2048.0f);
    }
    int ks = cc >> 1, g = cc & 1;
    int strip = slot >> 5, ln = slot & 31;
    size_t off = ((((size_t)b * NSTRIP + strip) * 4 + ks) * 64 + (g * 32 + ln)) * 8;
    _Float16* dh = flagged ? aH : bH;
    _Float16* dl = flagged ? aL : bL;
    *(f16x8*)(dh + off) = hh;
    *(f16x8*)(dl + off) = ll;
}

// ordered-float mapping: monotone bijection float -> uint32 under unsigned compare
__device__ __forceinline__ unsigned int ordf(float f) {
    unsigned int u = __float_as_uint(f);
    return (u & 0x80000000u) ? ~u : (u | 0x80000000u);
}

// ---------------- kernel 3: MFMA argmax, LDS-shared b-tiles ---------------
// D[j][i] = sum_c b[j][c]*a[i][c] via v_mfma_f32_32x32x16_f16, K=64 as 4
// k-steps, 3 passes (hh into cH; ah*bl + al*bh into cC, inputs pre-scaled
// x2048). sim = cH + cC/2048; dropped al*bl/2048^2 ~ 2^-22.
// Each wave owns 64 i-rows (2 strips). The block's 4 waves iterate the SAME
// j-tiles; each 8KB b-tile is staged into LDS ONCE per block (each wave
// reg-stages 2 of the 8 fragments: global load issued early, ds_write after
// the MFMAs — T14 split), double-buffered, ONE barrier per tile. This cuts
// b-side L2 traffic 4x vs per-wave register loads. Staged bytes are
// bit-identical to the round-3 register contents (k = ks*16 + g*8 + e both
// operands; C/D: col=lane&31, row=(reg&3)+8*(reg>>2)+4*(lane>>5)).
// Tail waves (base>=ni) do NOT exit: they must stage + hit barriers; their
// results are blocked by the il<ni commit guard (poison f16 is finite).
// First-max tie-break: per-lane rows scanned ascending with strict >, then
// packed-key (ordf(val)<<32 | ~j) merged across lane halves and chunks.
__global__ __launch_bounds__(256, 2) void argmax_kernel(
    const _Float16* __restrict__ aH, const _Float16* __restrict__ aL,
    const _Float16* __restrict__ bH, const _Float16* __restrict__ bL,
    const int* __restrict__ ilist, const int* __restrict__ counts,
    unsigned long long* __restrict__ amax)
{
    int ni = counts[0];
    if (blockIdx.x * 256 >= ni) return;              // block-uniform exit
    int nj = counts[1];
    int njt = (nj + 31) >> 5;
    int tpc = (njt + NCH - 1) / NCH;
    int s = blockIdx.y;
    int jt0 = s * tpc, jt1 = min(jt0 + tpc, njt);
    if (jt0 >= jt1) return;                          // block-uniform (s,nj only)
    int b = blockIdx.z;
    int wave = threadIdx.x >> 6, l = threadIdx.x & 63;
    int base = (blockIdx.x * 4 + wave) * 64;         // may exceed ni (tail waves)
    int g = l >> 5, ln = l & 31;
    int strip0 = base >> 5;                          // always < NSTRIP (grid bound)

    __shared__ f16x8 lds[2][8][64];                  // 2 x 8KB double buffer

    // a-frags (register-resident, per-wave; poison rows guarded at commit)
    const f16x8* apH = (const f16x8*)aH + ((size_t)b * NSTRIP + strip0) * 256 + l;
    const f16x8* apL = (const f16x8*)aL + ((size_t)b * NSTRIP + strip0) * 256 + l;
    f16x8 xh0 = apH[0],   xh1 = apH[64],  xh2 = apH[128], xh3 = apH[192];   // strip0 H
    f16x8 xl0 = apL[0],   xl1 = apL[64],  xl2 = apL[128], xl3 = apL[192];   // strip0 L
    f16x8 yh0 = apH[256], yh1 = apH[320], yh2 = apH[384], yh3 = apH[448];   // strip1 H
    f16x8 yl0 = apL[256], yl1 = apL[320], yl2 = apL[384], yl3 = apL[448];   // strip1 L

    // staging sources: this wave owns fragments f0=2*wave, f0+1
    // frag f<4 = bH k-step f; f>=4 = bL k-step f-4; lane l -> tile*256+ks*64+l
    int f0 = wave * 2;
    const f16x8* s0 = (const f16x8*)((f0 < 4) ? bH : bL) +
                      (size_t)b * NSTRIP * 256 + (size_t)(f0 & 3) * 64 + l;
    const f16x8* s1 = (const f16x8*)((f0 + 1 < 4) ? bH : bL) +
                      (size_t)b * NSTRIP * 256 + (size_t)((f0 + 1) & 3) * 64 + l;

    // prologue: stage tile jt0 into buf 0
    {
        f16x8 t0 = s0[(size_t)jt0 * 256];
        f16x8 t1 = s1[(size_t)jt0 * 256];
        lds[0][f0][l] = t0;
        lds[0][f0 + 1][l] = t1;
    }
    __syncthreads();

    float bv0 = -INFINITY, bv1 = -INFINITY;
    int bj0 = -1, bj1 = -1;
    int cur = 0;

    for (int jt = jt0; jt < jt1; ++jt, cur ^= 1) {
        // issue next-tile global loads early (complete under the MFMAs)
        f16x8 n0, n1;
        bool more = (jt + 1 < jt1);                  // block-uniform
        if (more) {
            n0 = s0[(size_t)(jt + 1) * 256];
            n1 = s1[(size_t)(jt + 1) * 256];
        }
        // compute current tile from LDS
        f16x8 bh0 = lds[cur][0][l], bh1 = lds[cur][1][l];
        f16x8 bh2 = lds[cur][2][l], bh3 = lds[cur][3][l];
        f16x8 bl0 = lds[cur][4][l], bl1 = lds[cur][5][l];
        f16x8 bl2 = lds[cur][6][l], bl3 = lds[cur][7][l];
        f32x16 cH0 = {}, cC0 = {}, cH1 = {}, cC1 = {};
        // strip 0
        cH0 = __builtin_amdgcn_mfma_f32_32x32x16_f16(bh0, xh0, cH0, 0, 0, 0);
        cC0 = __builtin_amdgcn_mfma_f32_32x32x16_f16(bh0, xl0, cC0, 0, 0, 0);
        cC0 = __builtin_amdgcn_mfma_f32_32x32x16_f16(bl0, xh0, cC0, 0, 0, 0);
        cH0 = __builtin_amdgcn_mfma_f32_32x32x16_f16(bh1, xh1, cH0, 0, 0, 0);
        cC0 = __builtin_amdgcn_mfma_f32_32x32x16_f16(bh1, xl1, cC0, 0, 0, 0);
        cC0 = __builtin_amdgcn_mfma_f32_32x32x16_f16(bl1, xh1, cC0, 0, 0, 0);
        cH0 = __builtin_amdgcn_mfma_f32_32x32x16_f16(bh2, xh2, cH0, 0, 0, 0);
        cC0 = __builtin_amdgcn_mfma_f32_32x32x16_f16(bh2, xl2, cC0, 0, 0, 0);
        cC0 = __builtin_amdgcn_mfma_f32_32x32x16_f16(bl2, xh2, cC0, 0, 0, 0);
        cH0 = __builtin_amdgcn_mfma_f32_32x32x16_f16(bh3, xh3, cH0, 0, 0, 0);
        cC0 = __builtin_amdgcn_mfma_f32_32x32x16_f16(bh3, xl3, cC0, 0, 0, 0);
        cC0 = __builtin_amdgcn_mfma_f32_32x32x16_f16(bl3, xh3, cC0, 0, 0, 0);
        // strip 1 (same b-frags)
        cH1 = __builtin_amdgcn_mfma_f32_32x32x16_f16(bh0, yh0, cH1, 0, 0, 0);
        cC1 = __builtin_amdgcn_mfma_f32_32x32x16_f16(bh0, yl0, cC1, 0, 0, 0);
        cC1 = __builtin_amdgcn_mfma_f32_32x32x16_f16(bl0, yh0, cC1, 0, 0, 0);
        cH1 = __builtin_amdgcn_mfma_f32_32x32x16_f16(bh1, yh1, cH1, 0, 0, 0);
        cC1 = __builtin_amdgcn_mfma_f32_32x32x16_f16(bh1, yl1, cC1, 0, 0, 0);
        cC1 = __builtin_amdgcn_mfma_f32_32x32x16_f16(bl1, yh1, cC1, 0, 0, 0);
        cH1 = __builtin_amdgcn_mfma_f32_32x32x16_f16(bh2, yh2, cH1, 0, 0, 0);
        cC1 = __builtin_amdgcn_mfma_f32_32x32x16_f16(bh2, yl2, cC1, 0, 0, 0);
        cC1 = __builtin_amdgcn_mfma_f32_32x32x16_f16(bl2, yh2, cC1, 0, 0, 0);
        cH1 = __builtin_amdgcn_mfma_f32_32x32x16_f16(bh3, yh3, cH1, 0, 0, 0);
        cC1 = __builtin_amdgcn_mfma_f32_32x32x16_f16(bh3, yl3, cC1, 0, 0, 0);
        cC1 = __builtin_amdgcn_mfma_f32_32x32x16_f16(bl3, yh3, cC1, 0, 0, 0);
        int jb = jt << 5;
        // scan registers in ascending-j order (strict > => first max)
#pragma unroll
        for (int r = 0; r < 16; ++r) {
            int row = (r & 3) + 8 * (r >> 2) + 4 * g;
            int j = jb + row;
            float v0 = fmaf(cC0[r], 4.8828125e-4f /*2^-11*/, cH0[r]);
            float v1 = fmaf(cC1[r], 4.8828125e-4f, cH1[r]);
            if (j < nj && v0 > bv0) { bv0 = v0; bj0 = j; }
            if (j < nj && v1 > bv1) { bv1 = v1; bj1 = j; }
        }
        // write next tile into the other buffer, then ONE barrier per tile
        if (more) {
            lds[cur ^ 1][f0][l] = n0;
            lds[cur ^ 1][f0 + 1][l] = n1;
        }
        __syncthreads();
    }

    unsigned long long k0 = ((unsigned long long)ordf(bv0) << 32) |
                            (unsigned long long)(~(unsigned int)bj0);
    unsigned long long k1 = ((unsigned long long)ordf(bv1) << 32) |
                            (unsigned long long)(~(unsigned int)bj1);
    unsigned long long o0 = __shfl_xor(k0, 32, 64);   // merge lane halves
    unsigned long long o1 = __shfl_xor(k1, 32, 64);
    if (o0 > k0) k0 = o0;
    if (o1 > k1) k1 = o1;
    int il0 = base + ln, il1 = base + 32 + ln;
    // high word > ordf(-inf) iff a (finite) candidate was found
    if (g == 0) {
        if (il0 < ni && (unsigned)(k0 >> 32) > 0x007FFFFFu)
            atomicMax(&amax[(size_t)b * HW + ilist[il0]], k0);
        if (il1 < ni && (unsigned)(k1 >> 32) > 0x007FFFFFu)
            atomicMax(&amax[(size_t)b * HW + ilist[il1]], k1);
    }
}

// ---------------- kernel 4: fused epilogue (copy + decode + gather) -------
__global__ void epilogue_kernel(const float4* __restrict__ x4, const float* __restrict__ x,
                                const int* __restrict__ mask,
                                const unsigned long long* __restrict__ amax,
                                const int* __restrict__ jlist, float4* __restrict__ out4) {
    const int q = HW / 4;                            // 2304
    int t = blockIdx.x * blockDim.x + threadIdx.x;   // 0 .. 2*192*q-1
    if (t >= 2 * 192 * q) return;
    int pos4 = t % q;
    int c = (t / q) % 192;
    int b = t / (192 * q);
    if (c < 128) {
        out4[t] = x4[((size_t)b * 128 + c) * q + pos4];
    } else {
        float4 v = make_float4(0.f, 0.f, 0.f, 0.f);
        float* vp = &v.x;
        int pos = pos4 * 4;
        const float* xf = x + (size_t)(b * 128 + (c - 128)) * HW;
#pragma unroll
        for (int k = 0; k < 4; k++) {
            int p = pos + k;
            if (mask[p] >= 1) {
                unsigned long long key = amax[(size_t)b * HW + p];
                int j = 0;                           // nj==0 -> argmax of all-NEG row = 0
                if (key != 0ull) j = jlist[(int)(~(unsigned int)key)];
                vp[k] = xf[j];
            }
        }
        out4[t] = v;
    }
}

extern "C" void kernel_launch(void* const* d_in, const int* in_sizes, int n_in,
                              void* d_out, int out_size, void* d_ws, size_t ws_size,
                              hipStream_t stream) {
    const float* x = (const float*)d_in[0];
    const int* mask = (const int*)d_in[1];
    float4* out4 = (float4*)d_out;

    // workspace layout (aH 128B-aligned):
    //   counts @0 (8B) | ilist @128 (36864) | jlist @36992 (36864)
    //   slotmap @73856 (36864) | amax @110720 (147456) | invAll @258176 (73728)
    //   aH @331904 | aL | bH | bL  -- each 2*288*4*64*8 f16 = 2359296 B
    // total = 331904 + 4*2359296 = 9769088 B
    char* ws = (char*)d_ws;
    int*   counts  = (int*)ws;
    int*   ilist   = (int*)(ws + 128);
    int*   jlist   = (int*)(ws + 36992);
    int*   slotmap = (int*)(ws + 73856);
    unsigned long long* amax = (unsigned long long*)(ws + 110720);
    float* invAll  = (float*)(ws + 258176);
    _Float16* aH = (_Float16*)(ws + 331904);
    _Float16* aL = (_Float16*)(ws + 331904 + 1 * 2359296);
    _Float16* bH = (_Float16*)(ws + 331904 + 2 * 2359296);
    _Float16* bL = (_Float16*)(ws + 331904 + 3 * 2359296);

    // 1) fused norm + compact + amax zeroing (blocks 0..575 norm, block 576 compact)
    prep_kernel<<<577, 256, 0, stream>>>(x, mask, ilist, jlist, slotmap, counts,
                                         invAll, amax);
    // 2) fragment-packed fp16x2 operands (position-order, coalesced)
    {
        dim3 grid(HW / 256, 8, 2);                   // 36 x (ks,g) x b
        pack_kernel<<<grid, 256, 0, stream>>>(x, slotmap, invAll, aH, aL, bH, bL);
    }
    // 3) MFMA argmax: grid (i-groups, j-chunks, batch), 256 i-rows/block,
    //    LDS-shared b-tiles
    {
        dim3 grid(NSTRIP / 8, NCH, 2);               // 36 x 16 x 2
        argmax_kernel<<<grid, 256, 0, stream>>>(aH, aL, bH, bL, ilist, counts, amax);
    }
    // 4) fused copy + decode + gather
    {
        int n = 2 * 192 * (HW / 4);
        epilogue_kernel<<<(n + 255) / 256, 256, 0, stream>>>((const float4*)x, x, mask,
                                                             amax, jlist, out4);
    }
}